// Round 11
// baseline (288.444 us; speedup 1.0000x reference)
//
#include <hip/hip_runtime.h>
#include <cstdint>
#include <cstddef>

// Problem dims (fixed by reference): x [8,1024,1024] -> M=8192, dim=1024, hidden=4096
#define DIM   1024
#define HID   4096
#define MROWS 8192

typedef __attribute__((ext_vector_type(8))) __bf16 bf16x8;
typedef __attribute__((ext_vector_type(4))) float  f32x4;

__device__ __forceinline__ unsigned short f2bf(float f) {
  unsigned int u = __float_as_uint(f);
  u += 0x7fffu + ((u >> 16) & 1u);   // round-to-nearest-even
  return (unsigned short)(u >> 16);
}
__device__ __forceinline__ float bf2f(unsigned int lo16) {
  return __uint_as_float(lo16 << 16);
}

// tanh-form GELU: ~7 VALU instrs vs ~25 for erff; deviation from exact ~1e-3.
__device__ __forceinline__ float fast_gelu(float v) {
  float u = v * (0.79788456080286536f + 0.035677408136300125f * v * v);
  float e = __builtin_amdgcn_exp2f(u * 2.8853900817779268f);   // exp(2u)
  float r = __builtin_amdgcn_rcpf(e + 1.0f);
  return v - v * r;   // = v * e/(e+1) = 0.5 v (1+tanh(u))
}

// ---- async global->LDS, 16B per lane (m97 pattern) ----
__device__ __forceinline__ void gld16(const void* g, void* l) {
  auto* gp = reinterpret_cast<__attribute__((address_space(1))) unsigned int*>(
      reinterpret_cast<uintptr_t>(g));
  auto* lp = reinterpret_cast<__attribute__((address_space(3))) unsigned int*>(
      reinterpret_cast<uintptr_t>(l));
  __builtin_amdgcn_global_load_lds(gp, lp, 16, 0, 0);
}

// ---- wave reduce (two values), 64 lanes, shuffle-only (no LDS/barriers) ----
__device__ __forceinline__ void wave_reduce2(float& a, float& b) {
#pragma unroll
  for (int off = 32; off > 0; off >>= 1) {
    a += __shfl_xor(a, off, 64);
    b += __shfl_xor(b, off, 64);
  }
}

// ---- block reduce (two values), 256 threads = 4 waves ----
// Leading __syncthreads makes back-to-back calls safe (shared red[] reuse).
__device__ __forceinline__ void block_reduce2(float& a, float& b, int tid) {
  __shared__ float red[8];
  __syncthreads();
  wave_reduce2(a, b);
  if ((tid & 63) == 0) { red[tid >> 6] = a; red[4 + (tid >> 6)] = b; }
  __syncthreads();
  a = red[0] + red[1] + red[2] + red[3];
  b = red[4] + red[5] + red[6] + red[7];
}

// ---- prep: |w| partial sums AND LN1, one dispatch ----
// blocks 0..2047:   absum partials (w1 then w2, 4096 floats each) -> part[bid]
// blocks 2048..4095: LN1, one WAVE per row (4 rows/block, shuffle-only —
//   R10 accounting says the barrier-heavy row kernels cost ~3x their BW floor)
__global__ __launch_bounds__(256)
void prep_kernel(const float* __restrict__ w1, const float* __restrict__ w2,
                 float* __restrict__ part,
                 const float* __restrict__ x, const float* __restrict__ g,
                 const float* __restrict__ b, unsigned short* __restrict__ xn) {
  int tid = threadIdx.x;
  int bid = blockIdx.x;
  if (bid < 2048) {
    const float* w = (bid < 1024) ? w1 : w2;
    int blk = bid & 1023;
    const float4* base = (const float4*)w + (size_t)blk * 1024;
    float s = 0.f;
#pragma unroll
    for (int i = 0; i < 4; ++i) {
      float4 v = base[tid + i * 256];
      s += fabsf(v.x) + fabsf(v.y) + fabsf(v.z) + fabsf(v.w);
    }
#pragma unroll
    for (int off = 32; off > 0; off >>= 1) s += __shfl_xor(s, off, 64);
    __shared__ float red[4];
    if ((tid & 63) == 0) red[tid >> 6] = s;
    __syncthreads();
    if (tid == 0) part[bid] = red[0] + red[1] + red[2] + red[3];
  } else {
    const int row  = (bid - 2048) * 4 + (tid >> 6);
    const int lane = tid & 63;
    const float4* xr = (const float4*)(x + (size_t)row * DIM);
    const float4* g4 = (const float4*)g;
    const float4* b4 = (const float4*)b;
    float4 v[4];
    float s = 0.f, ss = 0.f;
#pragma unroll
    for (int p = 0; p < 4; ++p) {
      v[p] = xr[lane + 64 * p];
      s  += v[p].x + v[p].y + v[p].z + v[p].w;
      ss += v[p].x * v[p].x + v[p].y * v[p].y + v[p].z * v[p].z + v[p].w * v[p].w;
    }
    wave_reduce2(s, ss);
    float mu  = s * (1.0f / DIM);
    float var = ss * (1.0f / DIM) - mu * mu;
    float rs  = rsqrtf(var + 1e-5f);
    uint2* dst = (uint2*)(xn + (size_t)row * DIM);
#pragma unroll
    for (int p = 0; p < 4; ++p) {
      float4 gg = g4[lane + 64 * p];
      float4 bb = b4[lane + 64 * p];
      uint2 r;
      r.x = (unsigned)f2bf((v[p].x - mu) * rs * gg.x + bb.x) |
            ((unsigned)f2bf((v[p].y - mu) * rs * gg.y + bb.y) << 16);
      r.y = (unsigned)f2bf((v[p].z - mu) * rs * gg.z + bb.z) |
            ((unsigned)f2bf((v[p].w - mu) * rs * gg.w + bb.w) << 16);
      dst[lane + 64 * p] = r;
    }
  }
}

// ---- ternary quantize + folded-LN2 weight vectors ----
// Mean reduce of part[] is WAVE-local now (4KB, L2-hot, deterministic ->
// identical mean in all waves; removes 2 block barriers per block).
// blocks 0..511:    q1 = clip(rint(w1/mean1)) bf16 {-1,0,1}; blk0 publishes scal[0].
// blocks 512..1535: block owns w2 row d: q2[d][k] = t*g2[k];
//   Sg[d] = mean2*sum g2*t; Cb[d] = mean2*sum b2*t + bias2[d]; blk512 -> scal[1].
__global__ __launch_bounds__(256)
void quant_kernel(const float* __restrict__ part,
                  const float* __restrict__ w1, unsigned short* __restrict__ q1,
                  const float* __restrict__ w2, unsigned short* __restrict__ q2,
                  const float* __restrict__ g2, const float* __restrict__ b2,
                  const float* __restrict__ bias2,
                  float* __restrict__ Sg, float* __restrict__ Cb,
                  float* __restrict__ scal) {
  int bid = blockIdx.x, tid = threadIdx.x;
  const int lane = tid & 63;
  // wave-local mean of the relevant weight: reduce 1024 partials (4 f4/lane)
  const float4* psrc = (const float4*)(part + ((bid < 512) ? 0 : 1024));
  float a = 0.f, dummy = 0.f;
#pragma unroll
  for (int p = 0; p < 4; ++p) {
    float4 pv = psrc[lane + 64 * p];
    a += pv.x + pv.y + pv.z + pv.w;
  }
  wave_reduce2(a, dummy);
  float mean = fmaxf(a * (1.0f / 4194304.0f), 1e-5f);
  float sc = 1.0f / mean;

  if (bid < 512) {
    if (bid == 0 && tid == 0) scal[0] = mean;
    const int n4 = 1048576;
    int i = bid * 256 + tid;
    for (; i < n4; i += 512 * 256) {
      float4 v = ((const float4*)w1)[i];
      float t0 = fminf(fmaxf(rintf(v.x * sc), -1.f), 1.f);
      float t1 = fminf(fmaxf(rintf(v.y * sc), -1.f), 1.f);
      float t2 = fminf(fmaxf(rintf(v.z * sc), -1.f), 1.f);
      float t3 = fminf(fmaxf(rintf(v.w * sc), -1.f), 1.f);
      uint2 r;
      r.x = (unsigned)f2bf(t0) | ((unsigned)f2bf(t1) << 16);
      r.y = (unsigned)f2bf(t2) | ((unsigned)f2bf(t3) << 16);
      ((uint2*)q1)[i] = r;
    }
  } else {
    const int d = bid - 512;
    if (d == 0 && tid == 0) scal[1] = mean;
    const float4* wr = (const float4*)(w2 + (size_t)d * HID);
    const float4* g4 = (const float4*)g2;
    const float4* b4 = (const float4*)b2;
    uint2* qr = (uint2*)(q2 + (size_t)d * HID);
    float s1 = 0.f, s2 = 0.f;
#pragma unroll
    for (int i = 0; i < 4; ++i) {
      int idx = tid + 256 * i;
      float4 wv = wr[idx], gv = g4[idx], bv = b4[idx];
      float t0 = fminf(fmaxf(rintf(wv.x * sc), -1.f), 1.f);
      float t1 = fminf(fmaxf(rintf(wv.y * sc), -1.f), 1.f);
      float t2 = fminf(fmaxf(rintf(wv.z * sc), -1.f), 1.f);
      float t3 = fminf(fmaxf(rintf(wv.w * sc), -1.f), 1.f);
      s1 += gv.x * t0 + gv.y * t1 + gv.z * t2 + gv.w * t3;
      s2 += bv.x * t0 + bv.y * t1 + bv.z * t2 + bv.w * t3;
      uint2 r;
      r.x = (unsigned)f2bf(t0 * gv.x) | ((unsigned)f2bf(t1 * gv.y) << 16);
      r.y = (unsigned)f2bf(t2 * gv.z) | ((unsigned)f2bf(t3 * gv.w) << 16);
      qr[idx] = r;
    }
    block_reduce2(s1, s2, tid);
    if (tid == 0) {
      Sg[d] = mean * s1;
      Cb[d] = mean * s2 + bias2[d];
    }
  }
}

// ---- row stats of h (read-only) -> per-row (a_m, b_m) for folded LN2 ----
// One WAVE per row (4 rows/block): 64 elems/lane (8 uint4), shuffle-only.
__global__ __launch_bounds__(256)
void rowstats_kernel(const unsigned short* __restrict__ h,
                     const float* __restrict__ meanp,
                     float2* __restrict__ murs) {
  const int row  = blockIdx.x * 4 + (threadIdx.x >> 6);
  const int lane = threadIdx.x & 63;
  const uint4* hr = (const uint4*)(h + (size_t)row * HID);
  float s = 0.f, ss = 0.f;
#pragma unroll
  for (int p = 0; p < 8; ++p) {
    uint4 pk = hr[lane + 64 * p];
    const unsigned int* pu = (const unsigned int*)&pk;
#pragma unroll
    for (int j = 0; j < 4; ++j) {
      float lo = bf2f(pu[j] & 0xffffu);
      float hi = __uint_as_float(pu[j] & 0xffff0000u);
      s += lo + hi; ss += lo * lo + hi * hi;
    }
  }
  wave_reduce2(s, ss);
  if (lane == 0) {
    float mu  = s * (1.0f / HID);
    float var = ss * (1.0f / HID) - mu * mu;
    float rs  = rsqrtf(var + 1e-5f);
    murs[row] = make_float2(rs * meanp[1], -rs * mu);
  }
}

// ---- GEMM C[m,n] = sum_k A[m,k]*B[n,k], fused epilogues (unchanged R10) ----
// A: bf16 [M,KK] row-major; B: bf16 [N,KK] row-major. KK compile-time
// (strength-reduced addressing; R9: VALUBusy 56->34%).
// Tile MT x 128, BK=64, 256 thr = 4 waves (2x2); MT=64 for GEMM2 (block count).
// LDS XOR-granule swizzle (R2: conflicts 8.4M->0); XCD band swizzle (R4:
// FETCH 286->158MB). MODE 1: gelu+bf16 store. MODE 0: folded LN2, fp32 store.
template <int MODE, int MT, int KK>
__global__ __launch_bounds__(256)
void gemm_bt(const unsigned short* __restrict__ A,
             const unsigned short* __restrict__ B,
             void* __restrict__ Cv,
             const float* __restrict__ wscale_ptr,
             const float* __restrict__ bias,
             const float2* __restrict__ murs,
             const float* __restrict__ Sg,
             const float* __restrict__ Cb,
             int N) {
  constexpr int IT = MT / 32;            // i-tiles per wave == A staging rounds
  __shared__ unsigned short sA[MT * 64];
  __shared__ unsigned short sB[128 * 64];

  const int tid  = threadIdx.x;
  const int lane = tid & 63;
  const int wave = tid >> 6;
  const int wm   = wave & 1;   // 0..1
  const int wn   = wave >> 1;  // 0..1

  // XCD-aware remap of (bm, bn)
  const int nbx  = gridDim.x;                    // column tiles
  const int id   = blockIdx.y * nbx + blockIdx.x;
  const int xcd  = id & 7;
  const int slot = id >> 3;
  const int bandsPerXcd = gridDim.y >> 3;
  const int band = xcd * bandsPerXcd + slot / nbx;
  const int col  = slot - (slot / nbx) * nbx;
  const int bm   = band * MT;
  const int bn   = col * 128;

  // staging: thread t, round i: row 32i+(t>>3), stored chunk t&7,
  // global chunk (t&7)^((t>>3)&7)
  const int csw = (((tid & 7) ^ ((tid >> 3) & 7))) * 8;
  const unsigned short* Ab = A + (size_t)(bm + (tid >> 3)) * KK + csw;
  const unsigned short* Bb = B + (size_t)(bn + (tid >> 3)) * KK + csw;

  f32x4 acc[IT][4] = {};

  // fragment read: row m = wm*(MT/2) + i*16 + (lane&15); k-granule (half h) =
  // h*4 + (lane>>4); stored position = granule ^ (lane&7)
  const int rowA = (wm * (MT / 2) + (lane & 15)) * 64;
  const int rowB = (wn * 64 + (lane & 15)) * 64;
  const int p0 = ((0 + (lane >> 4)) ^ (lane & 7)) * 8;   // k-half 0
  const int p1 = ((4 + (lane >> 4)) ^ (lane & 7)) * 8;   // k-half 1

  for (int k0 = 0; k0 < KK; k0 += 64) {
#pragma unroll
    for (int i = 0; i < IT; ++i)
      gld16(Ab + (size_t)(32 * i) * KK + k0, sA + i * 2048 + tid * 8);
#pragma unroll
    for (int i = 0; i < 4; ++i)
      gld16(Bb + (size_t)(32 * i) * KK + k0, sB + i * 2048 + tid * 8);
    __syncthreads();

#pragma unroll
    for (int h = 0; h < 2; ++h) {
      const int ph = h ? p1 : p0;
      bf16x8 af[IT], bfr[4];
#pragma unroll
      for (int i = 0; i < IT; ++i) af[i] = *(const bf16x8*)(sA + rowA + i * 1024 + ph);
#pragma unroll
      for (int j = 0; j < 4; ++j) bfr[j] = *(const bf16x8*)(sB + rowB + j * 1024 + ph);
#pragma unroll
      for (int i = 0; i < IT; ++i)
#pragma unroll
        for (int j = 0; j < 4; ++j)
          acc[i][j] = __builtin_amdgcn_mfma_f32_16x16x32_bf16(af[i], bfr[j], acc[i][j], 0, 0, 0);
    }
    __syncthreads();
  }

  if (MODE == 1) {
    const float wscale = *wscale_ptr;
    float bv[4];
#pragma unroll
    for (int j = 0; j < 4; ++j) bv[j] = bias[bn + wn * 64 + j * 16 + (lane & 15)];
#pragma unroll
    for (int i = 0; i < IT; ++i) {
      const int m0 = bm + wm * (MT / 2) + i * 16 + ((lane >> 4) << 2);
#pragma unroll
      for (int j = 0; j < 4; ++j) {
        const int n = bn + wn * 64 + j * 16 + (lane & 15);
#pragma unroll
        for (int r = 0; r < 4; ++r) {
          float v = fast_gelu(acc[i][j][r] * wscale + bv[j]);
          ((unsigned short*)Cv)[(size_t)(m0 + r) * N + n] = f2bf(v);
        }
      }
    }
  } else {
    float sg[4], cb[4];
#pragma unroll
    for (int j = 0; j < 4; ++j) {
      const int n = bn + wn * 64 + j * 16 + (lane & 15);
      sg[j] = Sg[n];
      cb[j] = Cb[n];
    }
#pragma unroll
    for (int i = 0; i < IT; ++i) {
      const int m0 = bm + wm * (MT / 2) + i * 16 + ((lane >> 4) << 2);
#pragma unroll
      for (int r = 0; r < 4; ++r) {
        float2 ab = murs[m0 + r];
#pragma unroll
        for (int j = 0; j < 4; ++j) {
          const int n = bn + wn * 64 + j * 16 + (lane & 15);
          ((float*)Cv)[(size_t)(m0 + r) * N + n] = ab.x * acc[i][j][r] + ab.y * sg[j] + cb[j];
        }
      }
    }
  }
}

extern "C" void kernel_launch(void* const* d_in, const int* in_sizes, int n_in,
                              void* d_out, int out_size, void* d_ws, size_t ws_size,
                              hipStream_t stream) {
  const float* x     = (const float*)d_in[0];
  const float* g1    = (const float*)d_in[1];
  const float* b1v   = (const float*)d_in[2];
  const float* w1    = (const float*)d_in[3];
  const float* bias1 = (const float*)d_in[4];
  const float* g2    = (const float*)d_in[5];
  const float* b2v   = (const float*)d_in[6];
  const float* w2    = (const float*)d_in[7];
  const float* bias2 = (const float*)d_in[8];
  float* out = (float*)d_out;

  char* ws = (char*)d_ws;
  float* scal          = (float*)ws;                 // [0]=mean|w1| [1]=mean|w2| (clipped)
  float* part          = (float*)(ws + 64);          // 2048 partial sums
  unsigned short* q1   = (unsigned short*)(ws + 16384);   // 4096x1024 bf16
  unsigned short* q2   = q1 + 4194304;                    // 1024x4096 bf16 (g2-scaled)
  unsigned short* xn   = q2 + 4194304;                    // 8192x1024 bf16
  unsigned short* h    = xn + 8388608;                    // 8192x4096 bf16 (gelu out)
  float2* murs         = (float2*)(h + 33554432);         // 8192 x {a_m, b_m}
  float* Sg            = (float*)(murs + 8192);           // 1024
  float* Cb            = Sg + 1024;                       // 1024

  prep_kernel<<<4096, 256, 0, stream>>>(w1, w2, part, x, g1, b1v, xn);
  quant_kernel<<<1536, 256, 0, stream>>>(part, w1, q1, w2, q2, g2, b2v, bias2, Sg, Cb, scal);
  gemm_bt<1, 128, DIM><<<dim3(HID / 128, MROWS / 128), 256, 0, stream>>>(
      xn, q1, h, scal + 0, bias1, nullptr, nullptr, nullptr, HID);
  rowstats_kernel<<<2048, 256, 0, stream>>>(h, scal, murs);
  gemm_bt<0, 64, HID><<<dim3(DIM / 128, MROWS / 64), 256, 0, stream>>>(
      h, q2, out, scal + 1, nullptr, murs, Sg, Cb, DIM);
}

// Round 12
// 262.351 us; speedup vs baseline: 1.0995x; 1.0995x over previous
//
#include <hip/hip_runtime.h>
#include <cstdint>
#include <cstddef>

// Problem dims (fixed by reference): x [8,1024,1024] -> M=8192, dim=1024, hidden=4096
#define DIM   1024
#define HID   4096
#define MROWS 8192

typedef __attribute__((ext_vector_type(8))) __bf16 bf16x8;
typedef __attribute__((ext_vector_type(4))) float  f32x4;
typedef __attribute__((ext_vector_type(4))) int    i32x4;

__device__ __forceinline__ unsigned short f2bf(float f) {
  unsigned int u = __float_as_uint(f);
  u += 0x7fffu + ((u >> 16) & 1u);   // round-to-nearest-even
  return (unsigned short)(u >> 16);
}
__device__ __forceinline__ float bf2f(unsigned int lo16) {
  return __uint_as_float(lo16 << 16);
}

// tanh-form GELU: ~7 VALU instrs vs ~25 for erff; deviation from exact ~1e-3.
__device__ __forceinline__ float fast_gelu(float v) {
  float u = v * (0.79788456080286536f + 0.035677408136300125f * v * v);
  float e = __builtin_amdgcn_exp2f(u * 2.8853900817779268f);   // exp(2u)
  float r = __builtin_amdgcn_rcpf(e + 1.0f);
  return v - v * r;   // = v * e/(e+1) = 0.5 v (1+tanh(u))
}

// ---- async global->LDS, 16B per lane (m97 pattern) ----
__device__ __forceinline__ void gld16(const void* g, void* l) {
  auto* gp = reinterpret_cast<__attribute__((address_space(1))) unsigned int*>(
      reinterpret_cast<uintptr_t>(g));
  auto* lp = reinterpret_cast<__attribute__((address_space(3))) unsigned int*>(
      reinterpret_cast<uintptr_t>(l));
  __builtin_amdgcn_global_load_lds(gp, lp, 16, 0, 0);
}

// ---- wave reduce (two values), 64 lanes, shuffle-only ----
__device__ __forceinline__ void wave_reduce2(float& a, float& b) {
#pragma unroll
  for (int off = 32; off > 0; off >>= 1) {
    a += __shfl_xor(a, off, 64);
    b += __shfl_xor(b, off, 64);
  }
}
__device__ __forceinline__ float wave_reduce_max(float m) {
#pragma unroll
  for (int off = 32; off > 0; off >>= 1) m = fmaxf(m, __shfl_xor(m, off, 64));
  return m;
}

// ---- block reduce (two values), 256 threads = 4 waves ----
__device__ __forceinline__ void block_reduce2(float& a, float& b, int tid) {
  __shared__ float red[8];
  __syncthreads();
  wave_reduce2(a, b);
  if ((tid & 63) == 0) { red[tid >> 6] = a; red[4 + (tid >> 6)] = b; }
  __syncthreads();
  a = red[0] + red[1] + red[2] + red[3];
  b = red[4] + red[5] + red[6] + red[7];
}

// ---- prep: |w| partial sums AND LN1(+i8 quant), one dispatch ----
// blocks 0..2047:    absum partials (w1 then w2) -> part[bid]
// blocks 2048..4095: LN1 one WAVE per row (4 rows/block): normalize, find
//   row max, quantize to int8 with per-row scale 127/max; store xn8 + invs.
__global__ __launch_bounds__(256)
void prep_kernel(const float* __restrict__ w1, const float* __restrict__ w2,
                 float* __restrict__ part,
                 const float* __restrict__ x, const float* __restrict__ g,
                 const float* __restrict__ b, unsigned int* __restrict__ xn8,
                 float* __restrict__ invs) {
  int tid = threadIdx.x;
  int bid = blockIdx.x;
  if (bid < 2048) {
    const float* w = (bid < 1024) ? w1 : w2;
    int blk = bid & 1023;
    const float4* base = (const float4*)w + (size_t)blk * 1024;
    float s = 0.f;
#pragma unroll
    for (int i = 0; i < 4; ++i) {
      float4 v = base[tid + i * 256];
      s += fabsf(v.x) + fabsf(v.y) + fabsf(v.z) + fabsf(v.w);
    }
#pragma unroll
    for (int off = 32; off > 0; off >>= 1) s += __shfl_xor(s, off, 64);
    __shared__ float red[4];
    if ((tid & 63) == 0) red[tid >> 6] = s;
    __syncthreads();
    if (tid == 0) part[bid] = red[0] + red[1] + red[2] + red[3];
  } else {
    const int row  = (bid - 2048) * 4 + (tid >> 6);
    const int lane = tid & 63;
    const float4* xr = (const float4*)(x + (size_t)row * DIM);
    const float4* g4 = (const float4*)g;
    const float4* b4 = (const float4*)b;
    float4 v[4];
    float s = 0.f, ss = 0.f;
#pragma unroll
    for (int p = 0; p < 4; ++p) {
      v[p] = xr[lane + 64 * p];
      s  += v[p].x + v[p].y + v[p].z + v[p].w;
      ss += v[p].x * v[p].x + v[p].y * v[p].y + v[p].z * v[p].z + v[p].w * v[p].w;
    }
    wave_reduce2(s, ss);
    float mu  = s * (1.0f / DIM);
    float var = ss * (1.0f / DIM) - mu * mu;
    float rs  = rsqrtf(var + 1e-5f);
    // normalized values + row max
    float n[4][4];
    float amax = 0.f;
#pragma unroll
    for (int p = 0; p < 4; ++p) {
      float4 gg = g4[lane + 64 * p];
      float4 bb = b4[lane + 64 * p];
      n[p][0] = (v[p].x - mu) * rs * gg.x + bb.x;
      n[p][1] = (v[p].y - mu) * rs * gg.y + bb.y;
      n[p][2] = (v[p].z - mu) * rs * gg.z + bb.z;
      n[p][3] = (v[p].w - mu) * rs * gg.w + bb.w;
#pragma unroll
      for (int c = 0; c < 4; ++c) amax = fmaxf(amax, fabsf(n[p][c]));
    }
    amax = wave_reduce_max(amax);
    float sc, iv;
    if (amax < 1e-20f) { sc = 0.f; iv = 0.f; }
    else               { sc = 127.0f / amax; iv = amax * (1.0f / 127.0f); }
    if (lane == 0) invs[row] = iv;
    unsigned int* dst = xn8 + (size_t)row * 256;   // 1024 i8 = 256 u32 per row
#pragma unroll
    for (int p = 0; p < 4; ++p) {
      unsigned r = 0;
#pragma unroll
      for (int c = 0; c < 4; ++c) {
        int q = (int)rintf(n[p][c] * sc);
        r |= ((unsigned)q & 0xffu) << (8 * c);
      }
      dst[lane + 64 * p] = r;
    }
  }
}

// ---- ternary quantize + folded-LN2 weight vectors ----
// blocks 0..511:    q1 int8 {-1,0,1} packed 4/u32 (grid-stride); blk0 -> scal[0].
// blocks 512..1535: w2 row d: q2 bf16 = t*g2[k]; Sg/Cb; blk512 -> scal[1].
// Mean reduce of part[] is wave-local (deterministic, identical in all waves).
__global__ __launch_bounds__(256)
void quant_kernel(const float* __restrict__ part,
                  const float* __restrict__ w1, unsigned int* __restrict__ q1,
                  const float* __restrict__ w2, unsigned short* __restrict__ q2,
                  const float* __restrict__ g2, const float* __restrict__ b2,
                  const float* __restrict__ bias2,
                  float* __restrict__ Sg, float* __restrict__ Cb,
                  float* __restrict__ scal) {
  int bid = blockIdx.x, tid = threadIdx.x;
  const int lane = tid & 63;
  const float4* psrc = (const float4*)(part + ((bid < 512) ? 0 : 1024));
  float a = 0.f, dummy = 0.f;
#pragma unroll
  for (int p = 0; p < 4; ++p) {
    float4 pv = psrc[lane + 64 * p];
    a += pv.x + pv.y + pv.z + pv.w;
  }
  wave_reduce2(a, dummy);
  float mean = fmaxf(a * (1.0f / 4194304.0f), 1e-5f);
  float sc = 1.0f / mean;

  if (bid < 512) {
    if (bid == 0 && tid == 0) scal[0] = mean;
    const int n4 = 1048576;
    int i = bid * 256 + tid;
    for (; i < n4; i += 512 * 256) {
      float4 v = ((const float4*)w1)[i];
      int t0 = (int)fminf(fmaxf(rintf(v.x * sc), -1.f), 1.f);
      int t1 = (int)fminf(fmaxf(rintf(v.y * sc), -1.f), 1.f);
      int t2 = (int)fminf(fmaxf(rintf(v.z * sc), -1.f), 1.f);
      int t3 = (int)fminf(fmaxf(rintf(v.w * sc), -1.f), 1.f);
      unsigned r = ((unsigned)t0 & 0xffu) | (((unsigned)t1 & 0xffu) << 8) |
                   (((unsigned)t2 & 0xffu) << 16) | (((unsigned)t3 & 0xffu) << 24);
      q1[i] = r;
    }
  } else {
    const int d = bid - 512;
    if (d == 0 && tid == 0) scal[1] = mean;
    const float4* wr = (const float4*)(w2 + (size_t)d * HID);
    const float4* g4 = (const float4*)g2;
    const float4* b4 = (const float4*)b2;
    uint2* qr = (uint2*)(q2 + (size_t)d * HID);
    float s1 = 0.f, s2 = 0.f;
#pragma unroll
    for (int i = 0; i < 4; ++i) {
      int idx = tid + 256 * i;
      float4 wv = wr[idx], gv = g4[idx], bv = b4[idx];
      float t0 = fminf(fmaxf(rintf(wv.x * sc), -1.f), 1.f);
      float t1 = fminf(fmaxf(rintf(wv.y * sc), -1.f), 1.f);
      float t2 = fminf(fmaxf(rintf(wv.z * sc), -1.f), 1.f);
      float t3 = fminf(fmaxf(rintf(wv.w * sc), -1.f), 1.f);
      s1 += gv.x * t0 + gv.y * t1 + gv.z * t2 + gv.w * t3;
      s2 += bv.x * t0 + bv.y * t1 + bv.z * t2 + bv.w * t3;
      uint2 r;
      r.x = (unsigned)f2bf(t0 * gv.x) | ((unsigned)f2bf(t1 * gv.y) << 16);
      r.y = (unsigned)f2bf(t2 * gv.z) | ((unsigned)f2bf(t3 * gv.w) << 16);
      qr[idx] = r;
    }
    block_reduce2(s1, s2, tid);
    if (tid == 0) {
      Sg[d] = mean * s1;
      Cb[d] = mean * s2 + bias2[d];
    }
  }
}

// ---- row stats of h (read-only) -> per-row (a_m, b_m) for folded LN2 ----
__global__ __launch_bounds__(256)
void rowstats_kernel(const unsigned short* __restrict__ h,
                     const float* __restrict__ meanp,
                     float2* __restrict__ murs) {
  const int row  = blockIdx.x * 4 + (threadIdx.x >> 6);
  const int lane = threadIdx.x & 63;
  const uint4* hr = (const uint4*)(h + (size_t)row * HID);
  float s = 0.f, ss = 0.f;
#pragma unroll
  for (int p = 0; p < 8; ++p) {
    uint4 pk = hr[lane + 64 * p];
    const unsigned int* pu = (const unsigned int*)&pk;
#pragma unroll
    for (int j = 0; j < 4; ++j) {
      float lo = bf2f(pu[j] & 0xffffu);
      float hi = __uint_as_float(pu[j] & 0xffff0000u);
      s += lo + hi; ss += lo * lo + hi * hi;
    }
  }
  wave_reduce2(s, ss);
  if (lane == 0) {
    float mu  = s * (1.0f / HID);
    float var = ss * (1.0f / HID) - mu * mu;
    float rs  = rsqrtf(var + 1e-5f);
    murs[row] = make_float2(rs * meanp[1], -rs * mu);
  }
}

// ---- GEMM1 (i8): h[m,n] = gelu( (sum_k x8[m,k]*t8[n,k]) * mean1*invs_m + b1[n] )
// A: int8 [M,1024]; B: int8 ternary [N,1024]. i32 MFMA accum is EXACT.
// 128x128 tile, BK=64 (64B rows), 256 thr = 4 waves (2x2), mfma_i32_16x16x64_i8.
// Staging bytes and MFMA instruction count are HALF the bf16 version (R12).
// LDS rows are 64B -> R2 swizzle: 16B chunk c of row r at pos c^((r>>1)&3);
// worst case 2-way bank alias = free (m136). XCD band swizzle as R4.
__global__ __launch_bounds__(256)
void gemm1_i8(const unsigned char* __restrict__ A,
              const unsigned char* __restrict__ B,
              unsigned short* __restrict__ H,
              const float* __restrict__ wscale_ptr,
              const float* __restrict__ invs,
              const float* __restrict__ bias) {
  __shared__ unsigned char sA[128 * 64];
  __shared__ unsigned char sB[128 * 64];

  const int tid  = threadIdx.x;
  const int lane = tid & 63;
  const int wave = tid >> 6;
  const int wm   = wave & 1;
  const int wn   = wave >> 1;

  // XCD-aware remap (nbx=32 col tiles, 64 bands, 8 bands/XCD)
  const int nbx  = gridDim.x;
  const int id   = blockIdx.y * nbx + blockIdx.x;
  const int xcd  = id & 7;
  const int slot = id >> 3;
  const int bandsPerXcd = gridDim.y >> 3;
  const int band = xcd * bandsPerXcd + slot / nbx;
  const int col  = slot - (slot / nbx) * nbx;
  const int bm   = band * 128;
  const int bn   = col * 128;

  // staging: thread t, round i: row 64i+(t>>2), stored chunk t&3,
  // global chunk (t&3)^((t>>3)&3)   [row>>1 = t>>3 within a round]
  const int csw = ((tid & 3) ^ ((tid >> 3) & 3)) * 16;
  const unsigned char* Ab = A + (size_t)(bm + (tid >> 2)) * 1024 + csw;
  const unsigned char* Bb = B + (size_t)(bn + (tid >> 2)) * 1024 + csw;

  i32x4 acc[4][4] = {};

  // fragment: row m = wm*64 + i*16 + (lane&15); k-granule g = lane>>4 (16B);
  // stored pos = g ^ ((m>>1)&3) = g ^ ((lane>>1)&3)  [i*16,wm*64 are mult of 8]
  const int rowA = (wm * 64 + (lane & 15)) * 64;
  const int rowB = (wn * 64 + (lane & 15)) * 64;
  const int kc = (((lane >> 4) ^ ((lane >> 1) & 3))) * 16;

  for (int k0 = 0; k0 < 1024; k0 += 64) {
    gld16(Ab + k0,              sA + tid * 16);
    gld16(Ab + 64 * 1024 + k0,  sA + 4096 + tid * 16);
    gld16(Bb + k0,              sB + tid * 16);
    gld16(Bb + 64 * 1024 + k0,  sB + 4096 + tid * 16);
    __syncthreads();

    i32x4 af[4], bfr[4];
#pragma unroll
    for (int i = 0; i < 4; ++i) af[i]  = *(const i32x4*)(sA + rowA + i * 1024 + kc);
#pragma unroll
    for (int j = 0; j < 4; ++j) bfr[j] = *(const i32x4*)(sB + rowB + j * 1024 + kc);
#pragma unroll
    for (int i = 0; i < 4; ++i)
#pragma unroll
      for (int j = 0; j < 4; ++j)
        acc[i][j] = __builtin_amdgcn_mfma_i32_16x16x64_i8(af[i], bfr[j], acc[i][j], 0, 0, 0);
    __syncthreads();
  }

  const float wscale = *wscale_ptr;
  float bv[4];
#pragma unroll
  for (int j = 0; j < 4; ++j) bv[j] = bias[bn + wn * 64 + j * 16 + (lane & 15)];
#pragma unroll
  for (int i = 0; i < 4; ++i) {
    const int m0 = bm + wm * 64 + i * 16 + ((lane >> 4) << 2);
    float asc[4];
#pragma unroll
    for (int r = 0; r < 4; ++r) asc[r] = wscale * invs[m0 + r];
#pragma unroll
    for (int j = 0; j < 4; ++j) {
      const int n = bn + wn * 64 + j * 16 + (lane & 15);
#pragma unroll
      for (int r = 0; r < 4; ++r) {
        float v = fast_gelu((float)acc[i][j][r] * asc[r] + bv[j]);
        H[(size_t)(m0 + r) * HID + n] = f2bf(v);
      }
    }
  }
}

// ---- GEMM2 (bf16, unchanged R11): out = a_m*acc + b_m*Sg[n] + Cb[n] ----
template <int MODE, int MT, int KK>
__global__ __launch_bounds__(256)
void gemm_bt(const unsigned short* __restrict__ A,
             const unsigned short* __restrict__ B,
             void* __restrict__ Cv,
             const float* __restrict__ wscale_ptr,
             const float* __restrict__ bias,
             const float2* __restrict__ murs,
             const float* __restrict__ Sg,
             const float* __restrict__ Cb,
             int N) {
  constexpr int IT = MT / 32;
  __shared__ unsigned short sA[MT * 64];
  __shared__ unsigned short sB[128 * 64];

  const int tid  = threadIdx.x;
  const int lane = tid & 63;
  const int wave = tid >> 6;
  const int wm   = wave & 1;
  const int wn   = wave >> 1;

  const int nbx  = gridDim.x;
  const int id   = blockIdx.y * nbx + blockIdx.x;
  const int xcd  = id & 7;
  const int slot = id >> 3;
  const int bandsPerXcd = gridDim.y >> 3;
  const int band = xcd * bandsPerXcd + slot / nbx;
  const int col  = slot - (slot / nbx) * nbx;
  const int bm   = band * MT;
  const int bn   = col * 128;

  const int csw = (((tid & 7) ^ ((tid >> 3) & 7))) * 8;
  const unsigned short* Ab = A + (size_t)(bm + (tid >> 3)) * KK + csw;
  const unsigned short* Bb = B + (size_t)(bn + (tid >> 3)) * KK + csw;

  f32x4 acc[IT][4] = {};

  const int rowA = (wm * (MT / 2) + (lane & 15)) * 64;
  const int rowB = (wn * 64 + (lane & 15)) * 64;
  const int p0 = ((0 + (lane >> 4)) ^ (lane & 7)) * 8;
  const int p1 = ((4 + (lane >> 4)) ^ (lane & 7)) * 8;

  for (int k0 = 0; k0 < KK; k0 += 64) {
#pragma unroll
    for (int i = 0; i < IT; ++i)
      gld16(Ab + (size_t)(32 * i) * KK + k0, sA + i * 2048 + tid * 8);
#pragma unroll
    for (int i = 0; i < 4; ++i)
      gld16(Bb + (size_t)(32 * i) * KK + k0, sB + i * 2048 + tid * 8);
    __syncthreads();

#pragma unroll
    for (int h = 0; h < 2; ++h) {
      const int ph = h ? p1 : p0;
      bf16x8 af[IT], bfr[4];
#pragma unroll
      for (int i = 0; i < IT; ++i) af[i] = *(const bf16x8*)(sA + rowA + i * 1024 + ph);
#pragma unroll
      for (int j = 0; j < 4; ++j) bfr[j] = *(const bf16x8*)(sB + rowB + j * 1024 + ph);
#pragma unroll
      for (int i = 0; i < IT; ++i)
#pragma unroll
        for (int j = 0; j < 4; ++j)
          acc[i][j] = __builtin_amdgcn_mfma_f32_16x16x32_bf16(af[i], bfr[j], acc[i][j], 0, 0, 0);
    }
    __syncthreads();
  }

  if (MODE == 1) {
    const float wscale = *wscale_ptr;
    float bv[4];
#pragma unroll
    for (int j = 0; j < 4; ++j) bv[j] = bias[bn + wn * 64 + j * 16 + (lane & 15)];
#pragma unroll
    for (int i = 0; i < IT; ++i) {
      const int m0 = bm + wm * (MT / 2) + i * 16 + ((lane >> 4) << 2);
#pragma unroll
      for (int j = 0; j < 4; ++j) {
        const int n = bn + wn * 64 + j * 16 + (lane & 15);
#pragma unroll
        for (int r = 0; r < 4; ++r) {
          float v = fast_gelu(acc[i][j][r] * wscale + bv[j]);
          ((unsigned short*)Cv)[(size_t)(m0 + r) * N + n] = f2bf(v);
        }
      }
    }
  } else {
    float sg[4], cb[4];
#pragma unroll
    for (int j = 0; j < 4; ++j) {
      const int n = bn + wn * 64 + j * 16 + (lane & 15);
      sg[j] = Sg[n];
      cb[j] = Cb[n];
    }
#pragma unroll
    for (int i = 0; i < IT; ++i) {
      const int m0 = bm + wm * (MT / 2) + i * 16 + ((lane >> 4) << 2);
#pragma unroll
      for (int r = 0; r < 4; ++r) {
        float2 ab = murs[m0 + r];
#pragma unroll
        for (int j = 0; j < 4; ++j) {
          const int n = bn + wn * 64 + j * 16 + (lane & 15);
          ((float*)Cv)[(size_t)(m0 + r) * N + n] = ab.x * acc[i][j][r] + ab.y * sg[j] + cb[j];
        }
      }
    }
  }
}

extern "C" void kernel_launch(void* const* d_in, const int* in_sizes, int n_in,
                              void* d_out, int out_size, void* d_ws, size_t ws_size,
                              hipStream_t stream) {
  const float* x     = (const float*)d_in[0];
  const float* g1    = (const float*)d_in[1];
  const float* b1v   = (const float*)d_in[2];
  const float* w1    = (const float*)d_in[3];
  const float* bias1 = (const float*)d_in[4];
  const float* g2    = (const float*)d_in[5];
  const float* b2v   = (const float*)d_in[6];
  const float* w2    = (const float*)d_in[7];
  const float* bias2 = (const float*)d_in[8];
  float* out = (float*)d_out;

  char* ws = (char*)d_ws;
  float* scal          = (float*)ws;                      // [0]=mean|w1| [1]=mean|w2|
  float* part          = (float*)(ws + 64);               // 2048 partials
  float* invs          = (float*)(ws + 16384);            // 8192 per-row dequant (32 KB)
  unsigned int* q1     = (unsigned int*)(ws + 65536);     // 4096x1024 i8 = 4 MB
  unsigned short* q2   = (unsigned short*)(ws + 65536 + 4194304);  // 8 MB bf16
  unsigned int* xn8    = (unsigned int*)((char*)q2 + 8388608);     // 8192x1024 i8 = 8 MB
  unsigned short* h    = (unsigned short*)((char*)xn8 + 8388608);  // 64 MB bf16
  float2* murs         = (float2*)((char*)h + 67108864);  // 8192 x {a_m,b_m}
  float* Sg            = (float*)(murs + 8192);           // 1024
  float* Cb            = Sg + 1024;                       // 1024

  prep_kernel<<<4096, 256, 0, stream>>>(w1, w2, part, x, g1, b1v, xn8, invs);
  quant_kernel<<<1536, 256, 0, stream>>>(part, w1, q1, w2, q2, g2, b2v, bias2, Sg, Cb, scal);
  gemm1_i8<<<dim3(HID / 128, MROWS / 128), 256, 0, stream>>>(
      (const unsigned char*)xn8, (const unsigned char*)q1, h, scal + 0, invs, bias1);
  rowstats_kernel<<<2048, 256, 0, stream>>>(h, scal, murs);
  gemm_bt<0, 64, HID><<<dim3(DIM / 128, MROWS / 64), 256, 0, stream>>>(
      h, q2, out, scal + 1, nullptr, murs, Sg, Cb, DIM);
}